// Round 2
// baseline (139.550 us; speedup 1.0000x reference)
//
#include <hip/hip_runtime.h>
#include <math.h>

#define BATCH 16384
#define CTX 10
#define NEG 5
#define DIM 128
#define B_PER_BLOCK 8
#define NBLOCKS (BATCH / B_PER_BLOCK)   // 2048

// logsigmoid(x) = min(x,0) - log1p(exp(-|x|))   (numerically stable)
__device__ __forceinline__ float logsig(float x) {
    return fminf(x, 0.f) - log1pf(expf(-fabsf(x)));
}

__global__ __launch_bounds__(256) void cbow_fused(
    const int* __restrict__ pos_u,      // [B, CTX]
    const int* __restrict__ pos_w,      // [B]
    const int* __restrict__ neg_w,      // [B, NEG]
    const float* __restrict__ u_weight, // [VOCAB, DIM]
    const float* __restrict__ w_weight, // [VOCAB, DIM]
    float* __restrict__ out)            // [1], pre-zeroed
{
    const int tid   = threadIdx.x;
    const int lane  = tid & 31;         // 0..31: 4 dims each
    const int b     = blockIdx.x * B_PER_BLOCK + (tid >> 5);
    const int col   = lane * 4;

    // --- lane-parallel index fetch: 3 masked loads instead of 16 broadcast loads ---
    // lanes 0..9 -> ctx indices, lane 10 -> pos_w, lanes 11..15 -> neg_w
    int myidx = 0;
    if (lane < CTX)                 myidx = pos_u[b * CTX + lane];
    else if (lane == CTX)           myidx = pos_w[b];
    else if (lane < CTX + 1 + NEG)  myidx = neg_w[b * NEG + (lane - CTX - 1)];

    // --- broadcast indices, issue all 16 row gathers with addresses ready ---
    float4 r[16];
#pragma unroll
    for (int i = 0; i < 16; ++i) {
        const int idx = __shfl(myidx, i, 32);
        const float* base = (i < CTX) ? u_weight : w_weight;
        r[i] = *reinterpret_cast<const float4*>(base + (size_t)idx * DIM + col);
    }

    // --- context sum (this lane's 4 dims) ---
    float4 su = r[0];
#pragma unroll
    for (int i = 1; i < CTX; ++i) {
        su.x += r[i].x; su.y += r[i].y; su.z += r[i].z; su.w += r[i].w;
    }
    // --- negative rows sum (reference sums over NEG before logsig) ---
    float4 wn = r[CTX + 1];
#pragma unroll
    for (int i = CTX + 2; i < 16; ++i) {
        wn.x += r[i].x; wn.y += r[i].y; wn.z += r[i].z; wn.w += r[i].w;
    }
    const float4 wp = r[CTX];

    float s_pos = su.x * wp.x + su.y * wp.y + su.z * wp.z + su.w * wp.w;
    float s_neg = su.x * wn.x + su.y * wn.y + su.z * wn.z + su.w * wn.w;

    // --- reduce across the 32-lane group (xor masks <=16 stay in-group) ---
#pragma unroll
    for (int m = 16; m >= 1; m >>= 1) {
        s_pos += __shfl_xor(s_pos, m, 64);
        s_neg += __shfl_xor(s_neg, m, 64);
    }

    // --- per-block LDS accumulation, then one global atomic per block ---
    __shared__ float part;
    if (tid == 0) part = 0.f;
    __syncthreads();
    if (lane == 0) {
        const float t = logsig(s_pos) + logsig(-s_neg);
        atomicAdd(&part, t);
    }
    __syncthreads();
    if (tid == 0) atomicAdd(out, -part);   // reference returns -loss
}

extern "C" void kernel_launch(void* const* d_in, const int* in_sizes, int n_in,
                              void* d_out, int out_size, void* d_ws, size_t ws_size,
                              hipStream_t stream) {
    const int*   pos_u    = (const int*)d_in[0];
    const int*   pos_w    = (const int*)d_in[1];
    const int*   neg_w    = (const int*)d_in[2];
    const float* u_weight = (const float*)d_in[3];
    const float* w_weight = (const float*)d_in[4];
    float*       out      = (float*)d_out;

    hipMemsetAsync(out, 0, sizeof(float), stream);
    cbow_fused<<<NBLOCKS, 256, 0, stream>>>(pos_u, pos_w, neg_w,
                                            u_weight, w_weight, out);
}

// Round 3
// 127.569 us; speedup vs baseline: 1.0939x; 1.0939x over previous
//
#include <hip/hip_runtime.h>
#include <math.h>

#define BATCH 16384
#define CTX 10
#define NEG 5
#define DIM 128
#define B_PER_BLOCK 8
#define NBLOCKS (BATCH / B_PER_BLOCK)   // 2048

// logsigmoid(x) = min(x,0) - log1p(exp(-|x|))   (numerically stable)
__device__ __forceinline__ float logsig(float x) {
    return fminf(x, 0.f) - log1pf(expf(-fabsf(x)));
}

__global__ __launch_bounds__(256) void cbow_partial(
    const int* __restrict__ pos_u,      // [B, CTX]
    const int* __restrict__ pos_w,      // [B]
    const int* __restrict__ neg_w,      // [B, NEG]
    const float* __restrict__ u_weight, // [VOCAB, DIM]
    const float* __restrict__ w_weight, // [VOCAB, DIM]
    float* __restrict__ partials)       // [NBLOCKS]
{
    const int tid   = threadIdx.x;
    const int lane  = tid & 31;         // 0..31: 4 dims each
    const int b     = blockIdx.x * B_PER_BLOCK + (tid >> 5);
    const int col   = lane * 4;

    // --- lane-parallel index fetch: 3 masked loads instead of 16 broadcast loads ---
    // lanes 0..9 -> ctx indices, lane 10 -> pos_w, lanes 11..15 -> neg_w
    int myidx = 0;
    if (lane < CTX)                 myidx = pos_u[b * CTX + lane];
    else if (lane == CTX)           myidx = pos_w[b];
    else if (lane < CTX + 1 + NEG)  myidx = neg_w[b * NEG + (lane - CTX - 1)];

    // broadcast: all 16 indices resident before any gather issues
    int idx[16];
#pragma unroll
    for (int i = 0; i < 16; ++i) idx[i] = __shfl(myidx, i, 32);

    // --- context sum: accumulate on the fly (compiler budgets in-flight loads) ---
    float4 su = make_float4(0.f, 0.f, 0.f, 0.f);
#pragma unroll
    for (int c = 0; c < CTX; ++c) {
        const float4 v = *reinterpret_cast<const float4*>(
            u_weight + (size_t)idx[c] * DIM + col);
        su.x += v.x; su.y += v.y; su.z += v.z; su.w += v.w;
    }

    // --- negatives: sum rows first (reference sums over NEG before logsig) ---
    float4 wn = make_float4(0.f, 0.f, 0.f, 0.f);
#pragma unroll
    for (int k = 0; k < NEG; ++k) {
        const float4 v = *reinterpret_cast<const float4*>(
            w_weight + (size_t)idx[CTX + 1 + k] * DIM + col);
        wn.x += v.x; wn.y += v.y; wn.z += v.z; wn.w += v.w;
    }

    // --- positive row ---
    const float4 wp = *reinterpret_cast<const float4*>(
        w_weight + (size_t)idx[CTX] * DIM + col);

    float s_pos = su.x * wp.x + su.y * wp.y + su.z * wp.z + su.w * wp.w;
    float s_neg = su.x * wn.x + su.y * wn.y + su.z * wn.z + su.w * wn.w;

    // --- reduce across the 32-lane group (xor masks <=16 stay in-group) ---
#pragma unroll
    for (int m = 16; m >= 1; m >>= 1) {
        s_pos += __shfl_xor(s_pos, m, 64);
        s_neg += __shfl_xor(s_neg, m, 64);
    }

    // --- per-block accumulation in LDS, one write per block ---
    __shared__ float part;
    if (tid == 0) part = 0.f;
    __syncthreads();
    if (lane == 0) {
        const float t = logsig(s_pos) + logsig(-s_neg);
        atomicAdd(&part, t);
    }
    __syncthreads();
    if (tid == 0) partials[blockIdx.x] = part;
}

__global__ __launch_bounds__(256) void cbow_reduce(
    const float* __restrict__ partials, // [NBLOCKS]
    float* __restrict__ out)
{
    const int tid = threadIdx.x;
    float s = 0.f;
    for (int i = tid; i < NBLOCKS; i += 256) s += partials[i];
#pragma unroll
    for (int m = 32; m >= 1; m >>= 1) s += __shfl_xor(s, m, 64);
    __shared__ float ws[4];
    if ((tid & 63) == 0) ws[tid >> 6] = s;
    __syncthreads();
    if (tid == 0) {
        float tot = ws[0] + ws[1] + ws[2] + ws[3];
        out[0] = -tot;   // reference returns -loss
    }
}

extern "C" void kernel_launch(void* const* d_in, const int* in_sizes, int n_in,
                              void* d_out, int out_size, void* d_ws, size_t ws_size,
                              hipStream_t stream) {
    const int*   pos_u    = (const int*)d_in[0];
    const int*   pos_w    = (const int*)d_in[1];
    const int*   neg_w    = (const int*)d_in[2];
    const float* u_weight = (const float*)d_in[3];
    const float* w_weight = (const float*)d_in[4];
    float*       out      = (float*)d_out;
    float*       partials = (float*)d_ws;   // NBLOCKS floats

    cbow_partial<<<NBLOCKS, 256, 0, stream>>>(pos_u, pos_w, neg_w,
                                              u_weight, w_weight, partials);
    cbow_reduce<<<1, 256, 0, stream>>>(partials, out);
}